// Round 3
// baseline (274.657 us; speedup 1.0000x reference)
//
#include <hip/hip_runtime.h>
#include <cstdint>
#include <cstddef>

#define EPS 1e-5f

typedef float    f4     __attribute__((ext_vector_type(4)));
typedef float    f2     __attribute__((ext_vector_type(2)));
typedef _Float16 half8  __attribute__((ext_vector_type(8)));
typedef _Float16 half4  __attribute__((ext_vector_type(4)));

#define S_XS 33
#define F_BLK 4    // features per k_main block (fsplit = 8)

// ---------------- K0: fp32 -> fp16 convert of f_fc2_w ----------------
__global__ __launch_bounds__(256) void k_conv(const float* __restrict__ in,
                                              _Float16* __restrict__ out) {
    int i = (blockIdx.x * 256 + threadIdx.x) * 4;
    f4 v = *(const f4*)(in + i);
    half4 h;
    h[0] = (_Float16)v[0]; h[1] = (_Float16)v[1];
    h[2] = (_Float16)v[2]; h[3] = (_Float16)v[3];
    *(half4*)(out + i) = h;
}

// ---------------- K1: weight-GRN -> softmax weights [8192][32] ----------------
__global__ __launch_bounds__(256) void k_weights(
    const float* __restrict__ x, const float* __restrict__ w1,
    const float* __restrict__ b1, const float* __restrict__ w2,
    const float* __restrict__ b2, const float* __restrict__ lng,
    const float* __restrict__ lnb, float* __restrict__ wts) {
    __shared__ float w1s[32 * S_XS];
    __shared__ float w2s[64 * S_XS];
    __shared__ float xsW[32 * S_XS];

    const int tid = threadIdx.x;
    const int lane = tid & 63;
    const int f = lane & 31;
    const int wv = tid >> 6;
    const int row0 = blockIdx.x * 32;

    for (int i = tid; i < 1024; i += 256) {
        int r = i >> 5, c = i & 31;
        w1s[r * S_XS + c] = w1[i];
        xsW[r * S_XS + c] = x[(size_t)row0 * 32 + i];
    }
    for (int i = tid; i < 2048; i += 256) {
        int r = i >> 5, c = i & 31;
        w2s[r * S_XS + c] = w2[i];
    }
    const float b1f = b1[f], b2a = b2[f], b2g = b2[f + 32];
    const float lgf = lng[f], lbf = lnb[f];
    __syncthreads();

    for (int rr = 0; rr < 8; ++rr) {
        const int r = wv * 8 + rr;
        float acc = b1f;
        #pragma unroll
        for (int k = 0; k < 32; ++k)
            acc = fmaf(w1s[f * S_XS + k], xsW[r * S_XS + k], acc);
        float hval = acc > 0.f ? acc : __expf(acc) - 1.f;

        float a = b2a, g = b2g;
        #pragma unroll
        for (int k = 0; k < 32; ++k) {
            float hk = __shfl(hval, k, 64);
            a = fmaf(w2s[f * S_XS + k], hk, a);
            g = fmaf(w2s[(f + 32) * S_XS + k], hk, g);
        }
        float xv = xsW[r * S_XS + f];
        float v = xv + a * (1.f / (1.f + __expf(-g)));

        float s = v;
        #pragma unroll
        for (int o = 1; o < 64; o <<= 1) s += __shfl_xor(s, o, 64);
        float mu = s * (1.f / 64.f);
        float d = v - mu;
        float sq = d * d;
        #pragma unroll
        for (int o = 1; o < 64; o <<= 1) sq += __shfl_xor(sq, o, 64);
        float y = d * rsqrtf(sq * (1.f / 64.f) + EPS) * lgf + lbf;

        float m = y;
        #pragma unroll
        for (int o = 1; o < 64; o <<= 1) m = fmaxf(m, __shfl_xor(m, o, 64));
        float e = __expf(y - m);
        float se = e;
        #pragma unroll
        for (int o = 1; o < 64; o <<= 1) se += __shfl_xor(se, o, 64);
        if (lane < 32) wts[(size_t)(row0 + r) * 32 + f] = e * 2.f / se;
    }
}

// ---------------- K2: fused per-feature GRNs + weighted combine ----------------
// Design T: block = 64 rows x F_BLK features, 4 waves, each wave owns 16 rows
// (MFMA m-side) x ALL 256 g (16 n-tiles). A = hv computed IN-LANE (lane l15
// owns row wv*16+l15) -> no hv LDS, no data barriers. GLU pairs acc[nt] vs
// acc[nt+8] in-register; LN sum over h = in-lane over nt + shfl_xor over l15.
// One phase-lock barrier per f keeps the 4 waves streaming the same W2[f]
// bytes for L1 hits.
__global__ __launch_bounds__(256, 3) void k_main(
    const float* __restrict__ x,
    const _Float16* __restrict__ w2h,   // [32][256][128] fp16
    const float* __restrict__ fc1w,     // [32][128]
    const float* __restrict__ fc1b,     // [32][128]
    const float* __restrict__ fc2b,     // [32][256]
    const float* __restrict__ skw,      // [32][128]
    const float* __restrict__ skb,      // [32][128]
    const float* __restrict__ lng,      // [32][128]
    const float* __restrict__ lnb,      // [32][128]
    const float* __restrict__ wts,      // [8192][32]
    float* __restrict__ out)            // [8192][128], pre-zeroed
{
    __shared__ float xs[64 * S_XS];     // 8448 B
    __shared__ float wss[64 * S_XS];    // 8448 B

    const int tid = threadIdx.x;
    const int tile = blockIdx.x >> 3;
    const int fbase = (blockIdx.x & 7) * F_BLK;
    const int row0 = tile * 64;

    for (int i = tid; i < 2048; i += 256) {
        int r = i >> 5, c = i & 31;
        xs[r * S_XS + c] = x[(size_t)row0 * 32 + i];
        wss[r * S_XS + c] = wts[(size_t)row0 * 32 + i];
    }

    const int lane = tid & 63;
    const int wv = tid >> 6;
    const int l15 = lane & 15;
    const int q = lane >> 4;
    const int rA = wv * 16 + l15;       // A-side local row owned by this lane

    float out_acc[8][4];
    #pragma unroll
    for (int nt = 0; nt < 8; ++nt)
        #pragma unroll
        for (int rg = 0; rg < 4; ++rg) out_acc[nt][rg] = 0.f;

    for (int fi = 0; fi < F_BLK; ++fi) {
        const int f = fbase + fi;
        __syncthreads();   // phase-lock waves (L1 share of W2[f] stream)

        // ---- A-frags: hv for row rA, all 128 h, in-lane ----
        const float xvA = xs[rA * S_XS + f];
        half8 A[4];
        #pragma unroll
        for (int kq = 0; kq < 4; ++kq) {
            const float* wp = fc1w + f * 128 + kq * 32 + 8 * q;
            const float* bp = fc1b + f * 128 + kq * 32 + 8 * q;
            f4 w0 = *(const f4*)wp, w1v = *(const f4*)(wp + 4);
            f4 b0 = *(const f4*)bp, b1v = *(const f4*)(bp + 4);
            half8 a;
            #pragma unroll
            for (int j = 0; j < 4; ++j) {
                float t = fmaf(xvA, w0[j], b0[j]);
                t = t > 0.f ? t : __expf(t) - 1.f;
                a[j] = (_Float16)t;
            }
            #pragma unroll
            for (int j = 0; j < 4; ++j) {
                float t = fmaf(xvA, w1v[j], b1v[j]);
                t = t > 0.f ? t : __expf(t) - 1.f;
                a[4 + j] = (_Float16)t;
            }
            A[kq] = a;
        }

        // ---- MFMA: acc[nt] = hv(16 rows) x W2[f][g-tile nt], k = 128 ----
        f4 acc[16];
        {
            f4 z; z[0] = 0.f; z[1] = 0.f; z[2] = 0.f; z[3] = 0.f;
            #pragma unroll
            for (int nt = 0; nt < 16; ++nt) acc[nt] = z;
        }
        const _Float16* bbase = w2h + ((size_t)f * 256 + l15) * 128 + 8 * q;
        half8 Bf[2][4];
        #pragma unroll
        for (int kq = 0; kq < 4; ++kq)
            Bf[0][kq] = *(const half8*)(bbase + kq * 32);
        #pragma unroll
        for (int nt = 0; nt < 16; ++nt) {
            const int cur = nt & 1;
            if (nt < 15) {
                const _Float16* bn = bbase + (nt + 1) * (16 * 128);
                #pragma unroll
                for (int kq = 0; kq < 4; ++kq)
                    Bf[cur ^ 1][kq] = *(const half8*)(bn + kq * 32);
            }
            #pragma unroll
            for (int kq = 0; kq < 4; ++kq)
                acc[nt] = __builtin_amdgcn_mfma_f32_16x16x32_f16(
                    A[kq], Bf[cur][kq], acc[nt], 0, 0, 0);
        }

        // ---- GLU + skip; per-row (4q+rg) sums in-lane over nt ----
        float xr[4], wrow[4];
        #pragma unroll
        for (int rg = 0; rg < 4; ++rg) {
            xr[rg] = xs[(wv * 16 + 4 * q + rg) * S_XS + f];
            wrow[rg] = wss[(wv * 16 + 4 * q + rg) * S_XS + f];
        }
        float vv[8][4];
        float s[4] = {0.f, 0.f, 0.f, 0.f}, sq[4] = {0.f, 0.f, 0.f, 0.f};
        #pragma unroll
        for (int nt = 0; nt < 8; ++nt) {
            const int h = nt * 16 + l15;
            float ba = fc2b[f * 256 + h];
            float bg = fc2b[f * 256 + 128 + h];
            float sw = skw[f * 128 + h];
            float sb = skb[f * 128 + h];
            #pragma unroll
            for (int rg = 0; rg < 4; ++rg) {
                float a = acc[nt][rg] + ba;
                float g = acc[nt + 8][rg] + bg;
                float sig = 1.f / (1.f + __expf(-g));
                float val = fmaf(xr[rg], sw, sb) + a * sig;
                vv[nt][rg] = val;
                s[rg] += val;
                sq[rg] = fmaf(val, val, sq[rg]);
            }
        }
        // reduce over l15 (h-axis): lanes xor 1,2,4,8
        #pragma unroll
        for (int o = 1; o < 16; o <<= 1) {
            #pragma unroll
            for (int rg = 0; rg < 4; ++rg) {
                s[rg] += __shfl_xor(s[rg], o, 64);
                sq[rg] += __shfl_xor(sq[rg], o, 64);
            }
        }
        // ---- LN + weighted accumulate ----
        float mu[4], wr[4];
        #pragma unroll
        for (int rg = 0; rg < 4; ++rg) {
            mu[rg] = s[rg] * (1.f / 128.f);
            float var = sq[rg] * (1.f / 128.f) - mu[rg] * mu[rg];
            wr[rg] = wrow[rg] * rsqrtf(fmaxf(var, 0.f) + EPS);
        }
        #pragma unroll
        for (int nt = 0; nt < 8; ++nt) {
            const int h = nt * 16 + l15;
            float lg = lng[f * 128 + h];
            float lb = lnb[f * 128 + h];
            #pragma unroll
            for (int rg = 0; rg < 4; ++rg) {
                float u = (vv[nt][rg] - mu[rg]) * wr[rg];
                out_acc[nt][rg] = fmaf(u, lg, fmaf(wrow[rg], lb, out_acc[nt][rg]));
            }
        }
    }

    // ---- combine: direct atomics (8 partial adds per element, fp32) ----
    #pragma unroll
    for (int nt = 0; nt < 8; ++nt) {
        #pragma unroll
        for (int rg = 0; rg < 4; ++rg) {
            const int r = row0 + wv * 16 + 4 * q + rg;
            atomicAdd(&out[(size_t)r * 128 + nt * 16 + l15], out_acc[nt][rg]);
        }
    }
}

extern "C" void kernel_launch(void* const* d_in, const int* in_sizes, int n_in,
                              void* d_out, int out_size, void* d_ws, size_t ws_size,
                              hipStream_t stream) {
    const float* x     = (const float*)d_in[0];
    const float* wg1w  = (const float*)d_in[1];
    const float* wg1b  = (const float*)d_in[2];
    const float* wg2w  = (const float*)d_in[3];
    const float* wg2b  = (const float*)d_in[4];
    const float* wglng = (const float*)d_in[5];
    const float* wglnb = (const float*)d_in[6];
    const float* fc1w  = (const float*)d_in[7];
    const float* fc1b  = (const float*)d_in[8];
    const float* fc2w  = (const float*)d_in[9];
    const float* fc2b  = (const float*)d_in[10];
    const float* skw   = (const float*)d_in[11];
    const float* skb   = (const float*)d_in[12];
    const float* lng   = (const float*)d_in[13];
    const float* lnb   = (const float*)d_in[14];
    float* out = (float*)d_out;

    _Float16* w2h = (_Float16*)d_ws;                  // 2 MB fp16 f_fc2_w
    float* wts = (float*)((char*)d_ws + (2u << 20));  // 1 MB softmax weights

    k_conv<<<dim3(1024), dim3(256), 0, stream>>>(fc2w, w2h);
    k_weights<<<dim3(256), dim3(256), 0, stream>>>(x, wg1w, wg1b, wg2w, wg2b,
                                                   wglng, wglnb, wts);
    hipMemsetAsync(out, 0, (size_t)out_size * sizeof(float), stream);
    k_main<<<dim3(1024), dim3(256), 0, stream>>>(x, w2h, fc1w, fc1b, fc2b,
                                                 skw, skb, lng, lnb, wts, out);
}

// Round 4
// 178.184 us; speedup vs baseline: 1.5414x; 1.5414x over previous
//
#include <hip/hip_runtime.h>
#include <cstdint>
#include <cstddef>

#define EPS 1e-5f

typedef float    f4     __attribute__((ext_vector_type(4)));
typedef float    f2     __attribute__((ext_vector_type(2)));
typedef _Float16 half8  __attribute__((ext_vector_type(8)));
typedef _Float16 half4  __attribute__((ext_vector_type(4)));

#define S_XS 33
#define F_BLK 8        // features per k_main block (fsplit = 4)
#define CHUNK 8192     // halves per (f,kq) chunk = 16 KB

#define GLD_LDS16(gp, lp)                                        \
    __builtin_amdgcn_global_load_lds(                            \
        (const __attribute__((address_space(1))) void*)(gp),     \
        (__attribute__((address_space(3))) void*)(lp), 16, 0, 0)

// ---------------- K0: f_fc2_w fp32 -> fp16, chunked layout ----------------
// out[f][kq][g][j] = in[f][g][kq*32+j]   (j in [0,32)) — each (f,kq) chunk is
// 16 KB contiguous so k_main can stage it with global_load_lds width=16.
__global__ __launch_bounds__(256) void k_conv(const float* __restrict__ in,
                                              _Float16* __restrict__ out) {
    int t = blockIdx.x * 256 + threadIdx.x;   // 131072 threads x 8 halves
    int j0 = (t & 3) * 8;
    int g  = (t >> 2) & 255;
    int fk = t >> 10;                          // f*4 + kq
    int f = fk >> 2, kq = fk & 3;
    const float* ip = in + ((size_t)f * 256 + g) * 128 + kq * 32 + j0;
    f4 v0 = *(const f4*)ip, v1 = *(const f4*)(ip + 4);
    half8 h;
    #pragma unroll
    for (int i = 0; i < 4; ++i) { h[i] = (_Float16)v0[i]; h[4 + i] = (_Float16)v1[i]; }
    *(half8*)(out + (size_t)t * 8) = h;
}

// ---------------- K1: weight-GRN -> softmax weights [8192][32] ----------------
__global__ __launch_bounds__(256) void k_weights(
    const float* __restrict__ x, const float* __restrict__ w1,
    const float* __restrict__ b1, const float* __restrict__ w2,
    const float* __restrict__ b2, const float* __restrict__ lng,
    const float* __restrict__ lnb, float* __restrict__ wts) {
    __shared__ float w1s[32 * S_XS];
    __shared__ float w2s[64 * S_XS];
    __shared__ float xsW[32 * S_XS];

    const int tid = threadIdx.x;
    const int lane = tid & 63;
    const int f = lane & 31;
    const int wv = tid >> 6;
    const int row0 = blockIdx.x * 32;

    for (int i = tid; i < 1024; i += 256) {
        int r = i >> 5, c = i & 31;
        w1s[r * S_XS + c] = w1[i];
        xsW[r * S_XS + c] = x[(size_t)row0 * 32 + i];
    }
    for (int i = tid; i < 2048; i += 256) {
        int r = i >> 5, c = i & 31;
        w2s[r * S_XS + c] = w2[i];
    }
    const float b1f = b1[f], b2a = b2[f], b2g = b2[f + 32];
    const float lgf = lng[f], lbf = lnb[f];
    __syncthreads();

    for (int rr = 0; rr < 8; ++rr) {
        const int r = wv * 8 + rr;
        float acc = b1f;
        #pragma unroll
        for (int k = 0; k < 32; ++k)
            acc = fmaf(w1s[f * S_XS + k], xsW[r * S_XS + k], acc);
        float hval = acc > 0.f ? acc : __expf(acc) - 1.f;

        float a = b2a, g = b2g;
        #pragma unroll
        for (int k = 0; k < 32; ++k) {
            float hk = __shfl(hval, k, 64);
            a = fmaf(w2s[f * S_XS + k], hk, a);
            g = fmaf(w2s[(f + 32) * S_XS + k], hk, g);
        }
        float xv = xsW[r * S_XS + f];
        float v = xv + a * (1.f / (1.f + __expf(-g)));

        float s = v;
        #pragma unroll
        for (int o = 1; o < 64; o <<= 1) s += __shfl_xor(s, o, 64);
        float mu = s * (1.f / 64.f);
        float d = v - mu;
        float sq = d * d;
        #pragma unroll
        for (int o = 1; o < 64; o <<= 1) sq += __shfl_xor(sq, o, 64);
        float y = d * rsqrtf(sq * (1.f / 64.f) + EPS) * lgf + lbf;

        float m = y;
        #pragma unroll
        for (int o = 1; o < 64; o <<= 1) m = fmaxf(m, __shfl_xor(m, o, 64));
        float e = __expf(y - m);
        float se = e;
        #pragma unroll
        for (int o = 1; o < 64; o <<= 1) se += __shfl_xor(se, o, 64);
        if (lane < 32) wts[(size_t)(row0 + r) * 32 + f] = e * 2.f / se;
    }
}

// ---------------- K2: fused per-feature GRNs + weighted combine ----------------
// Block = 64 rows x F_BLK features; 4 waves, wave wv owns rows [16wv,16wv+16)
// (MFMA m-side, A = hv computed in-lane) x all 256 g. B = W2 chunks staged
// global->LDS (global_load_lds x16, double-buffered, 1 barrier/chunk), read
// as contiguous ds_read_b128 (conflict-free). GLU pairs acc[nt]/acc[nt+8]
// in-register; LN in-wave via shfl_xor over l15.
__global__ __launch_bounds__(256, 3) void k_main(
    const float* __restrict__ x,
    const _Float16* __restrict__ w2c,   // [32][4][256][32] fp16 chunks
    const float* __restrict__ fc1w,     // [32][128]
    const float* __restrict__ fc1b,     // [32][128]
    const float* __restrict__ fc2b,     // [32][256]
    const float* __restrict__ skw,      // [32][128]
    const float* __restrict__ skb,      // [32][128]
    const float* __restrict__ lng,      // [32][128]
    const float* __restrict__ lnb,      // [32][128]
    const float* __restrict__ wts,      // [8192][32]
    float* __restrict__ out)            // [8192][128], pre-zeroed
{
    __shared__ __align__(16) _Float16 bchunk[2][CHUNK];   // 32 KB
    __shared__ float xs[64 * S_XS];                       // 8448 B
    __shared__ float wss[64 * S_XS];                      // 8448 B

    const int tid = threadIdx.x;
    const int tile = blockIdx.x >> 2;
    const int fbase = (blockIdx.x & 3) * F_BLK;
    const int row0 = tile * 64;

    for (int i = tid; i < 2048; i += 256) {
        int r = i >> 5, c = i & 31;
        xs[r * S_XS + c] = x[(size_t)row0 * 32 + i];
        wss[r * S_XS + c] = wts[(size_t)row0 * 32 + i];
    }

    const int lane = tid & 63;
    const int wv = tid >> 6;
    const int l15 = lane & 15;
    const int q = lane >> 4;
    const int rA = wv * 16 + l15;       // row owned by this lane (A-side)

    const _Float16* w2base = w2c + (size_t)fbase * 4 * CHUNK;

    // stage chunk cg (global index within block) into buffer b: 256 lanes x 16 B x 4
    auto stage = [&](int cg, int b) {
        const _Float16* gp = w2base + (size_t)cg * CHUNK;
        #pragma unroll
        for (int r = 0; r < 4; ++r) {
            const _Float16* g = gp + (r * 256 + tid) * 8;
            _Float16* l = &bchunk[b][(r * 256 + tid) * 8];
            GLD_LDS16(g, l);
        }
    };

    float out_acc[8][4];
    #pragma unroll
    for (int nt = 0; nt < 8; ++nt)
        #pragma unroll
        for (int rg = 0; rg < 4; ++rg) out_acc[nt][rg] = 0.f;

    stage(0, 0);
    __syncthreads();   // xs/wss staged + chunk 0 complete (vmcnt drained)

    int cg = 0;
    for (int fi = 0; fi < F_BLK; ++fi) {
        const int f = fbase + fi;
        const float xvA = xs[rA * S_XS + f];

        f4 acc[16];
        {
            f4 z; z[0] = 0.f; z[1] = 0.f; z[2] = 0.f; z[3] = 0.f;
            #pragma unroll
            for (int nt = 0; nt < 16; ++nt) acc[nt] = z;
        }

        #pragma unroll
        for (int kq = 0; kq < 4; ++kq, ++cg) {
            if (cg + 1 < F_BLK * 4) stage(cg + 1, (cg + 1) & 1);

            // A-frag for this k-chunk, in-lane: h = kq*32 + 8q + j
            half8 A;
            {
                const float* wp = fc1w + f * 128 + kq * 32 + 8 * q;
                const float* bp = fc1b + f * 128 + kq * 32 + 8 * q;
                f4 w0 = *(const f4*)wp, w1v = *(const f4*)(wp + 4);
                f4 b0 = *(const f4*)bp, b1v = *(const f4*)(bp + 4);
                #pragma unroll
                for (int j = 0; j < 4; ++j) {
                    float t0 = fmaf(xvA, w0[j], b0[j]);
                    float t1 = fmaf(xvA, w1v[j], b1v[j]);
                    t0 = t0 > 0.f ? t0 : __expf(t0) - 1.f;
                    t1 = t1 > 0.f ? t1 : __expf(t1) - 1.f;
                    A[j] = (_Float16)t0;
                    A[4 + j] = (_Float16)t1;
                }
            }

            // B-frags from LDS: chunk[g][j2], lane (l15,q) tile nt reads
            // g = nt*16 + l15, j2 = 8q..8q+7 -> contiguous 1 KB per wave-read
            const _Float16* bb = &bchunk[cg & 1][8 * q + l15 * 32];
            half8 B[8];
            #pragma unroll
            for (int nt = 0; nt < 8; ++nt)
                B[nt] = *(const half8*)(bb + nt * (16 * 32));
            #pragma unroll
            for (int nt = 0; nt < 8; ++nt)
                acc[nt] = __builtin_amdgcn_mfma_f32_16x16x32_f16(A, B[nt], acc[nt], 0, 0, 0);
            #pragma unroll
            for (int nt = 0; nt < 8; ++nt)
                B[nt] = *(const half8*)(bb + (nt + 8) * (16 * 32));
            #pragma unroll
            for (int nt = 0; nt < 8; ++nt)
                acc[nt + 8] = __builtin_amdgcn_mfma_f32_16x16x32_f16(A, B[nt], acc[nt + 8], 0, 0, 0);

            __syncthreads();   // chunk cg reads done everywhere; stage(cg+1) drained
        }

        // ---- GLU + skip; per-row sums in-lane over nt ----
        float xr[4], wrow[4];
        #pragma unroll
        for (int rg = 0; rg < 4; ++rg) {
            xr[rg] = xs[(wv * 16 + 4 * q + rg) * S_XS + f];
            wrow[rg] = wss[(wv * 16 + 4 * q + rg) * S_XS + f];
        }
        float vv[8][4];
        float s[4] = {0.f, 0.f, 0.f, 0.f}, sq[4] = {0.f, 0.f, 0.f, 0.f};
        #pragma unroll
        for (int nt = 0; nt < 8; ++nt) {
            const int h = nt * 16 + l15;
            float ba = fc2b[f * 256 + h];
            float bg = fc2b[f * 256 + 128 + h];
            float sw = skw[f * 128 + h];
            float sb = skb[f * 128 + h];
            #pragma unroll
            for (int rg = 0; rg < 4; ++rg) {
                float a = acc[nt][rg] + ba;
                float g = acc[nt + 8][rg] + bg;
                float sig = 1.f / (1.f + __expf(-g));
                float val = fmaf(xr[rg], sw, sb) + a * sig;
                vv[nt][rg] = val;
                s[rg] += val;
                sq[rg] = fmaf(val, val, sq[rg]);
            }
        }
        #pragma unroll
        for (int o = 1; o < 16; o <<= 1) {
            #pragma unroll
            for (int rg = 0; rg < 4; ++rg) {
                s[rg] += __shfl_xor(s[rg], o, 64);
                sq[rg] += __shfl_xor(sq[rg], o, 64);
            }
        }
        float mu[4], wr[4];
        #pragma unroll
        for (int rg = 0; rg < 4; ++rg) {
            mu[rg] = s[rg] * (1.f / 128.f);
            float var = sq[rg] * (1.f / 128.f) - mu[rg] * mu[rg];
            wr[rg] = wrow[rg] * rsqrtf(fmaxf(var, 0.f) + EPS);
        }
        #pragma unroll
        for (int nt = 0; nt < 8; ++nt) {
            const int h = nt * 16 + l15;
            float lg = lng[f * 128 + h];
            float lb = lnb[f * 128 + h];
            #pragma unroll
            for (int rg = 0; rg < 4; ++rg) {
                float u = (vv[nt][rg] - mu[rg]) * wr[rg];
                out_acc[nt][rg] = fmaf(u, lg, fmaf(wrow[rg], lb, out_acc[nt][rg]));
            }
        }
    }

    // ---- combine: 4 partial adds per element (fsplit=4), fp32 atomics ----
    #pragma unroll
    for (int nt = 0; nt < 8; ++nt) {
        #pragma unroll
        for (int rg = 0; rg < 4; ++rg) {
            const int r = row0 + wv * 16 + 4 * q + rg;
            atomicAdd(&out[(size_t)r * 128 + nt * 16 + l15], out_acc[nt][rg]);
        }
    }
}

extern "C" void kernel_launch(void* const* d_in, const int* in_sizes, int n_in,
                              void* d_out, int out_size, void* d_ws, size_t ws_size,
                              hipStream_t stream) {
    const float* x     = (const float*)d_in[0];
    const float* wg1w  = (const float*)d_in[1];
    const float* wg1b  = (const float*)d_in[2];
    const float* wg2w  = (const float*)d_in[3];
    const float* wg2b  = (const float*)d_in[4];
    const float* wglng = (const float*)d_in[5];
    const float* wglnb = (const float*)d_in[6];
    const float* fc1w  = (const float*)d_in[7];
    const float* fc1b  = (const float*)d_in[8];
    const float* fc2w  = (const float*)d_in[9];
    const float* fc2b  = (const float*)d_in[10];
    const float* skw   = (const float*)d_in[11];
    const float* skb   = (const float*)d_in[12];
    const float* lng   = (const float*)d_in[13];
    const float* lnb   = (const float*)d_in[14];
    float* out = (float*)d_out;

    _Float16* w2c = (_Float16*)d_ws;                  // 2 MB fp16 chunked f_fc2_w
    float* wts = (float*)((char*)d_ws + (2u << 20));  // 1 MB softmax weights

    k_conv<<<dim3(512), dim3(256), 0, stream>>>(fc2w, w2c);
    k_weights<<<dim3(256), dim3(256), 0, stream>>>(x, wg1w, wg1b, wg2w, wg2b,
                                                   wglng, wglnb, wts);
    hipMemsetAsync(out, 0, (size_t)out_size * sizeof(float), stream);
    k_main<<<dim3(512), dim3(256), 0, stream>>>(x, w2c, fc1w, fc1b, fc2b,
                                                skw, skb, lng, lnb, wts, out);
}